// Round 1
// baseline (15.946 us; speedup 1.0000x reference)
//
#include <hip/hip_runtime.h>

// VocabParallelEmbeddingWithTopping: per-token routed embedding gather.
// out[t, :] = (wi[t] == -1 ? base_weight[id[t], :] : delta_weights[wi[t], id[t], :])
//
// N = 8192 tokens, D = 1024 fp32. One block per token, 256 threads,
// each thread copies one float4 (16 B) -> one 4 KiB row per block.

static constexpr int kVocab    = 32000;
static constexpr int kEmbedDim = 1024;

__global__ __launch_bounds__(256) void routed_embed_kernel(
    const int* __restrict__ input_ids,
    const int* __restrict__ weight_indices,
    const float* __restrict__ base_weight,
    const float* __restrict__ delta_weights,
    float* __restrict__ out) {
    const int t  = blockIdx.x;
    const int id = input_ids[t];       // uniform per block (broadcast)
    const int wi = weight_indices[t];  // uniform per block

    const float* src = (wi < 0)
        ? base_weight + (size_t)id * kEmbedDim
        : delta_weights + ((size_t)wi * kVocab + (size_t)id) * kEmbedDim;

    const float4* __restrict__ s4 = reinterpret_cast<const float4*>(src);
    float4* __restrict__ o4 =
        reinterpret_cast<float4*>(out + (size_t)t * kEmbedDim);

    // 256 threads x float4 = 1024 floats = one full row.
    o4[threadIdx.x] = s4[threadIdx.x];
}

extern "C" void kernel_launch(void* const* d_in, const int* in_sizes, int n_in,
                              void* d_out, int out_size, void* d_ws, size_t ws_size,
                              hipStream_t stream) {
    const int*   input_ids      = (const int*)d_in[0];
    const int*   weight_indices = (const int*)d_in[1];
    const float* base_weight    = (const float*)d_in[2];
    const float* delta_weights  = (const float*)d_in[3];
    float*       out            = (float*)d_out;

    const int num_tokens = in_sizes[0];  // 8192

    routed_embed_kernel<<<num_tokens, 256, 0, stream>>>(
        input_ids, weight_indices, base_weight, delta_weights, out);
}